// Round 6
// baseline (271.958 us; speedup 1.0000x reference)
//
#include <hip/hip_runtime.h>

using u16 = unsigned short;
using u64 = unsigned long long;
typedef short s16x8 __attribute__((ext_vector_type(8)));
typedef _Float16 f16x8 __attribute__((ext_vector_type(8)));
typedef float f32x4 __attribute__((ext_vector_type(4)));

// Problem constants (fixed by reference)
constexpr int BATCH = 64, SEQ = 1024, FEAT = 512, NBINS = 32;
constexpr int N = BATCH * SEQ;              // 65536 samples
constexpr int TAB = 131072;                 // hash table slots (2N), pow2
constexpr unsigned TABMASK = TAB - 1;
constexpr u64 EMPTY = ~0ull;                // combined <= 2^32-1, safe sentinel
constexpr double FXSCALE = 67108864.0;      // 2^26 fixed-point for stat atomics
constexpr int NSHADOW = 64;                 // shadow accumulators

// NOTE: JAX reference under default config runs int64 as int32;
// left_shift(env, 32) on int32 is 0 in XLA -> combined id is the 32-bit key
// ONLY (env dropped). Verified across rounds: absmax 0.0.
// NOTE (R3 lesson): NO __threadfence() in wide kernels — agent-scope fences
// on 8-XCD MI355X do L2 writeback/invalidate; 1024 blocks x fence = +235 us.
// NOTE (R4 lesson): project was staging-bound, not MFMA-bound. A-frag for
// 16x16x32 is 32 contiguous bytes per lane -> direct global->reg loads,
// no LDS, no barriers.
// NOTE (R5): bench infra failed ("container failed twice"); same source
// resubmitted unchanged.

// Workspace layout (bytes)
constexpr size_t OFF_KEYS = 0;              // u64[TAB]       1048576 (memset 0xFF)
constexpr size_t OFF_HEAD = 1048576;        // i32[TAB]       524288  (memset 0xFF -> -1)
constexpr size_t OFF_CNT = 1572864;         // u32[TAB]       524288  (memset 0x00)
constexpr size_t OFF_SHAD = 2097152;        // u64[64][1024]  524288  (memset 0x00)
constexpr size_t OFF_QD = 2621504;          // f64[16384]     131072  (Q = P/sigma, f64)
constexpr size_t OFF_CD = 2752576;          // f64[32]        256
constexpr size_t OFF_CF = 2818304;          // f32[32]        128
constexpr size_t OFF_SLOT = 2818432;        // i32[N]         262144
constexpr size_t OFF_NEXT = 3080576;        // i32[N]         262144
constexpr size_t OFF_QFRAG = 3342720;       // u16[16384]     32768 f16 B-frags
// qfrag layout: [ch(4)][ks(4)][bt(2)][lane(64)][j(8)] f16 bits
// element = B[k][bin], k = ch*128+ks*32+(lane>>4)*8+j, bin = bt*16+(lane&15)

__device__ inline u16 f2h(float f) {  // f32 -> f16 RNE (hardware cvt)
  _Float16 h = (_Float16)f;
  return __builtin_bit_cast(u16, h);
}

// ---------------- Kernel A: per-column sum / sumsq of f32 input.
// f64 regs; deterministic int fixed-point atomics into 64 shadow arrays.
__global__ __launch_bounds__(256, 4) void colstats_kernel(
    const float4* __restrict__ xv,  // f32 features, 8388608 float4s
    u64* __restrict__ shad) {
  const int t = threadIdx.x;
  const int L = blockIdx.x * 256 + t;  // 1024 blocks * 256 = 262144 threads
  double s0 = 0, s1 = 0, s2 = 0, s3 = 0, q0 = 0, q1 = 0, q2 = 0, q3 = 0;
  for (int mm = 0; mm < 32; mm += 8) {
    float4 v[8];
#pragma unroll
    for (int u = 0; u < 8; u++) v[u] = xv[L + (mm + u) * 262144];
#pragma unroll
    for (int u = 0; u < 8; u++) {
      double a = (double)v[u].x, b = (double)v[u].y;
      double c = (double)v[u].z, d = (double)v[u].w;
      s0 += a; s1 += b; s2 += c; s3 += d;
      q0 += a * a; q1 += b * b; q2 += c * c; q3 += d * d;
    }
  }
  __shared__ double red[256 * 8];  // 16 KB
  red[t * 8 + 0] = s0; red[t * 8 + 1] = s1; red[t * 8 + 2] = s2; red[t * 8 + 3] = s3;
  red[t * 8 + 4] = q0; red[t * 8 + 5] = q1; red[t * 8 + 6] = q2; red[t * 8 + 7] = q3;
  __syncthreads();
  if (t < 128) {
    // threads t and t+128 own the same 4 columns (262144 % 128 == 0)
    double v[8];
#pragma unroll
    for (int u = 0; u < 8; u++) v[u] = red[t * 8 + u] + red[(t + 128) * 8 + u];
    const int c0 = 4 * t;
    u64* sh = shad + (size_t)(blockIdx.x & (NSHADOW - 1)) * 1024;
#pragma unroll
    for (int u = 0; u < 4; u++) {
      long long a = (long long)llrint(v[u] * FXSCALE);
      long long b = (long long)llrint(v[4 + u] * FXSCALE);
      atomicAdd(&sh[c0 + u], (u64)a);
      atomicAdd(&sh[512 + c0 + u], (u64)b);
    }
  }
}

// ---------------- Kernel B: merge shadows (fixed order), finalize mean/inv-sigma
// (f64), emit Qd f64 (recheck), f16 B-fragments in MFMA lane order, cd, cf.
__global__ __launch_bounds__(512) void finalize_kernel(
    const float* __restrict__ P,  // f32 [512][32]
    const u64* __restrict__ shad,
    double* __restrict__ Qd, u16* __restrict__ qfrag,
    double* __restrict__ cd, float* __restrict__ cf) {
  __shared__ double meanArr[FEAT];
  __shared__ double invArr[FEAT];
  __shared__ double part[16][NBINS];
  const int t = threadIdx.x;  // t = feature index, 512 threads
  long long isum = 0, isumsq = 0;
  for (int sh = 0; sh < NSHADOW; sh++) {  // fixed order (int adds: exact anyway)
    isum += (long long)shad[sh * 1024 + t];
    isumsq += (long long)shad[sh * 1024 + 512 + t];
  }
  const double Nd = (double)N;
  const double tot = 1e-4 + Nd;
  double s = (double)isum * (1.0 / FXSCALE);
  double ss = (double)isumsq * (1.0 / FXSCALE);
  double bm = s / Nd;
  double bv = (ss - s * s / Nd) / (Nd - 1.0);  // unbiased var
  double mean = bm * Nd / tot;
  double M2 = 1e-4 + bv * Nd + bm * bm * 1e-4 * Nd / tot;
  double var = M2 / tot;
  double inv = 1.0 / sqrt(var + 1e-8);
  meanArr[t] = mean;
  invArr[t] = inv;
  // scatter f16 B-fragments (MFMA B lane order) + f64 Q for recheck
  const int ch = t >> 7, ks = (t >> 5) & 3, kg = (t >> 3) & 3, jlo = t & 7;
#pragma unroll
  for (int j = 0; j < NBINS; j++) {
    double qd = (double)P[t * NBINS + j] * inv;
    Qd[t * NBINS + j] = qd;
    const int lane = (j & 15) | (kg << 4);
    const int bt = j >> 4;
    qfrag[(size_t)((((ch * 4 + ks) * 2 + bt) * 64 + lane) * 8 + jlo)] =
        f2h((float)qd);
  }
  __syncthreads();
  // c reduction: thread t handles bin j=t&31, feature block g=t>>5 (32 feats)
  {
    const int j = t & 31, g = t >> 5;
    double p = 0.0;
    for (int f = g * 32; f < g * 32 + 32; f++) {
      double qd = (double)P[f * NBINS + j] * invArr[f];
      p += meanArr[f] * qd;
    }
    part[g][j] = p;
  }
  __syncthreads();
  if (t < NBINS) {
    double c = 0.0;
    for (int g = 0; g < 16; g++) c += part[g][t];  // fixed order -> deterministic
    cd[t] = c;
    cf[t] = (float)c;
  }
}

// ---------------- Kernel C: single-term f16 MFMA projection, direct
// global->register A-fragments (no LDS, no barriers). Lane l of wave w loads
// X[rowBase+w*16+(l&15)][ch*128+ks*32+(l>>4)*8 .. +8] — 32 contiguous bytes,
// wave touches 16 rows x 128 B (full cache lines). Margin error unchanged
// from R3/R4 (bit-identical f16 inputs): TAU = 4e-3 covers it; borderline
// bins re-decided by the wave-cooperative f64 dot. Key assembly via
// __shfl_xor OR-reduce within 16-lane groups (replaces keyParts LDS).
constexpr float TAU = 4e-3f;
__global__ __launch_bounds__(256) void project_kernel(
    const float* __restrict__ feat,
    const u16* __restrict__ qfrag, const float* __restrict__ cf,
    const double* __restrict__ Qd, const double* __restrict__ cd,
    u64* __restrict__ keys_tab, int* __restrict__ head,
    unsigned* __restrict__ cnt, int* __restrict__ slot, int* __restrict__ nxt) {
  const int t = threadIdx.x;
  const int lane = t & 63;
  const int w = t >> 6;  // wave id: owns rows rowBase + w*16 .. +16, all 32 bins
  const int rowBase = blockIdx.x * 64;
  const int arow = rowBase + w * 16 + (lane & 15);     // A-frag row
  const float* xbase = feat + (size_t)arow * FEAT + (lane >> 4) * 8;

  f32x4 acc0 = {0.f, 0.f, 0.f, 0.f};  // bins 0..15
  f32x4 acc1 = {0.f, 0.f, 0.f, 0.f};  // bins 16..31
  for (int ch = 0; ch < 4; ch++) {  // K chunks of 128
    // B-fragments for this chunk -> 32 VGPRs (coalesced, L2-hot)
    s16x8 B[4][2];
#pragma unroll
    for (int ks = 0; ks < 4; ks++)
#pragma unroll
      for (int bt = 0; bt < 2; bt++)
        B[ks][bt] = *(const s16x8*)&qfrag[(size_t)((((ch * 4 + ks) * 2 + bt) * 64 + lane) * 8)];
#pragma unroll
    for (int ks = 0; ks < 4; ks++) {
      float4 x0 = *(const float4*)(xbase + ch * 128 + ks * 32);
      float4 x1 = *(const float4*)(xbase + ch * 128 + ks * 32 + 4);
      f16x8 a;
      a[0] = (_Float16)x0.x; a[1] = (_Float16)x0.y;
      a[2] = (_Float16)x0.z; a[3] = (_Float16)x0.w;
      a[4] = (_Float16)x1.x; a[5] = (_Float16)x1.y;
      a[6] = (_Float16)x1.z; a[7] = (_Float16)x1.w;
      acc0 = __builtin_amdgcn_mfma_f32_16x16x32_f16(
          a, __builtin_bit_cast(f16x8, B[ks][0]), acc0, 0, 0, 0);
      acc1 = __builtin_amdgcn_mfma_f32_16x16x32_f16(
          a, __builtin_bit_cast(f16x8, B[ks][1]), acc1, 0, 0, 0);
    }
  }
  // C/D layout (verified): col(bin) = lane&15, row = (lane>>4)*4 + reg
  const int colbin = lane & 15;
  float m0[4], m1[4];
  bool b0[4], b1[4];
  const float c0v = cf[colbin], c1v = cf[16 + colbin];
#pragma unroll
  for (int rg = 0; rg < 4; rg++) {
    m0[rg] = acc0[rg] - c0v;
    m1[rg] = acc1[rg] - c1v;
    b0[rg] = m0[rg] > 0.0f;
    b1[rg] = m1[rg] > 0.0f;
  }
  // wave-cooperative f64 recheck of borderline bins (uniform control flow)
#pragma unroll
  for (int bt = 0; bt < 2; bt++)
#pragma unroll
    for (int rg = 0; rg < 4; rg++) {
      const float mv = (bt == 0) ? m0[rg] : m1[rg];
      u64 mask = __ballot(fabsf(mv) < TAU);
      while (mask) {
        const int L = (int)__builtin_ctzll(mask);
        mask &= mask - 1;
        const int jj = bt * 16 + (L & 15);
        const int row = rowBase + w * 16 + (L >> 4) * 4 + rg;
        const float* xr = feat + (size_t)row * FEAT + lane * 8;
        const double* qp = Qd + (size_t)(lane * 8) * NBINS + jj;
        double p = 0.0;
#pragma unroll
        for (int u = 0; u < 8; u++) p = fma((double)xr[u], qp[u * NBINS], p);
#pragma unroll
        for (int off = 32; off > 0; off >>= 1) p += __shfl_xor(p, off, 64);
        const bool bit = p > cd[jj];
        if (lane == L) {
          if (bt == 0) b0[rg] = bit; else b1[rg] = bit;
        }
      }
    }
  // per-row key: OR-reduce each rg's bits over the 16-lane group.
  // Row g*4+rg (g = lane>>4) gets contributions only from lanes g*16..g*16+15.
  unsigned kb0 = (b0[0] ? (1u << colbin) : 0u) | (b1[0] ? (1u << (16 + colbin)) : 0u);
  unsigned kb1 = (b0[1] ? (1u << colbin) : 0u) | (b1[1] ? (1u << (16 + colbin)) : 0u);
  unsigned kb2 = (b0[2] ? (1u << colbin) : 0u) | (b1[2] ? (1u << (16 + colbin)) : 0u);
  unsigned kb3 = (b0[3] ? (1u << colbin) : 0u) | (b1[3] ? (1u << (16 + colbin)) : 0u);
#pragma unroll
  for (int off = 1; off < 16; off <<= 1) {
    kb0 |= __shfl_xor(kb0, off, 64);
    kb1 |= __shfl_xor(kb1, off, 64);
    kb2 |= __shfl_xor(kb2, off, 64);
    kb3 |= __shfl_xor(kb3, off, 64);
  }
  // lanes with (lane&15) < 4 insert row (lane>>4)*4 + (lane&15)
  const int sub = lane & 15;
  if (sub < 4) {
    const unsigned key = sub == 0 ? kb0 : sub == 1 ? kb1 : sub == 2 ? kb2 : kb3;
    const int i = rowBase + w * 16 + (lane >> 4) * 4 + sub;
    const u64 combined = (u64)key;  // JAX int32 semantics: env<<32 vanished
    unsigned idx = (unsigned)((combined * 0x9E3779B97F4A7C15ull) >> 47) & TABMASK;
    for (;;) {
      u64 prev = atomicCAS(&keys_tab[idx], EMPTY, combined);
      if (prev == EMPTY || prev == combined) break;
      idx = (idx + 1) & TABMASK;
    }
    slot[i] = (int)idx;
    atomicAdd(&cnt[idx], 1u);
    nxt[i] = atomicExch(&head[idx], i);
  }
}

// ---------------- Kernel D: occurrence rank -> reward (order-independent)
__global__ __launch_bounds__(256) void count_kernel(
    const int* __restrict__ slot, const int* __restrict__ nxt,
    const int* __restrict__ head, const unsigned* __restrict__ cnt,
    float* __restrict__ out) {
  const int i = blockIdx.x * 256 + threadIdx.x;
  const int sl = slot[i];
  const unsigned c = cnt[sl];
  float r = 1.0f;
  if (c > 1u) {
    int j = head[sl];
    int occ = 1;
    while (j >= 0) {
      occ += (j < i) ? 1 : 0;
      j = nxt[j];
    }
    r = 1.0f / sqrtf((float)occ);
  }
  out[i] = r;
}

extern "C" void kernel_launch(void* const* d_in, const int* in_sizes, int n_in,
                              void* d_out, int out_size, void* d_ws, size_t ws_size,
                              hipStream_t stream) {
  const float4* xv = (const float4*)d_in[0];  // features f32 [64*1024][512]
  const float* feat = (const float*)d_in[0];
  const float* proj = (const float*)d_in[1];  // random_projection f32 [512][32]
  float* out = (float*)d_out;                 // [65536] f32
  char* ws = (char*)d_ws;

  u64* keys_tab = (u64*)(ws + OFF_KEYS);
  int* head = (int*)(ws + OFF_HEAD);
  unsigned* cnt = (unsigned*)(ws + OFF_CNT);
  u64* shad = (u64*)(ws + OFF_SHAD);
  double* Qd = (double*)(ws + OFF_QD);
  double* cd = (double*)(ws + OFF_CD);
  float* cf = (float*)(ws + OFF_CF);
  int* slot = (int*)(ws + OFF_SLOT);
  int* nxt = (int*)(ws + OFF_NEXT);
  u16* qfrag = (u16*)(ws + OFF_QFRAG);

  // init: keys_tab + head -> 0xFF (EMPTY / -1); cnt + shadows -> 0
  (void)hipMemsetAsync(ws + OFF_KEYS, 0xFF, OFF_CNT - OFF_KEYS, stream);
  (void)hipMemsetAsync(ws + OFF_CNT, 0x00, OFF_QD - OFF_CNT, stream);

  colstats_kernel<<<1024, 256, 0, stream>>>(xv, shad);
  finalize_kernel<<<1, 512, 0, stream>>>(proj, shad, Qd, qfrag, cd, cf);
  project_kernel<<<N / 64, 256, 0, stream>>>(feat, qfrag, cf, Qd, cd,
                                             keys_tab, head, cnt, slot, nxt);
  count_kernel<<<N / 256, 256, 0, stream>>>(slot, nxt, head, cnt, out);
}

// Round 7
// 266.093 us; speedup vs baseline: 1.0220x; 1.0220x over previous
//
#include <hip/hip_runtime.h>

using u16 = unsigned short;
using u64 = unsigned long long;
typedef short s16x8 __attribute__((ext_vector_type(8)));
typedef _Float16 f16x8 __attribute__((ext_vector_type(8)));
typedef float f32x4 __attribute__((ext_vector_type(4)));

// Problem constants (fixed by reference)
constexpr int BATCH = 64, SEQ = 1024, FEAT = 512, NBINS = 32;
constexpr int N = BATCH * SEQ;              // 65536 samples
constexpr int TAB = 131072;                 // hash table slots (2N), pow2
constexpr unsigned TABMASK = TAB - 1;
constexpr u64 EMPTY = ~0ull;                // combined <= 2^32-1, safe sentinel
constexpr double FXSCALE = 67108864.0;      // 2^26 fixed-point for stat atomics
constexpr int NSHADOW = 64;                 // shadow accumulators

// NOTE: JAX reference under default config runs int64 as int32;
// left_shift(env, 32) on int32 is 0 in XLA -> combined id is the 32-bit key
// ONLY (env dropped). Verified across rounds: absmax 0.0.
// NOTE (R3 lesson): NO __threadfence() in wide kernels — agent-scope fences
// on 8-XCD MI355X do L2 writeback/invalidate; 1024 blocks x fence = +235 us.
// NOTE (R6 lesson): project has been ~15 us (near L3 floor) since R1; the
// single-block finalize (1 CU pulling 512 KB at HBM latency) is the suspect
// tail. This round: parallel shadow merge + slim finalize + fused init.

// Workspace layout (bytes)
constexpr size_t OFF_KEYS = 0;              // u64[TAB]       1048576 (init 0xFF)
constexpr size_t OFF_HEAD = 1048576;        // i32[TAB]       524288  (init 0xFF -> -1)
constexpr size_t OFF_CNT = 1572864;         // u32[TAB]       524288  (init 0x00)
constexpr size_t OFF_SHAD = 2097152;        // u64[64][1024]  524288  (init 0x00)
constexpr size_t OFF_QD = 2621504;          // f64[16384]     131072  (Q = P/sigma, f64)
constexpr size_t OFF_CD = 2752576;          // f64[32]        256
constexpr size_t OFF_CF = 2818304;          // f32[32]        128
constexpr size_t OFF_SLOT = 2818432;        // i32[N]         262144
constexpr size_t OFF_NEXT = 3080576;        // i32[N]         262144
constexpr size_t OFF_QFRAG = 3342720;       // u16[16384]     32768 f16 B-frags
constexpr size_t OFF_MERGE = 3375488;       // i64[1024]      8192 merged col sums
// qfrag layout: [ch(4)][ks(4)][bt(2)][lane(64)][j(8)] f16 bits
// element = B[k][bin], k = ch*128+ks*32+(lane>>4)*8+j, bin = bt*16+(lane&15)

// init region: [0, 1572864) = 0xFF (keys+head), [1572864, 2621440) = 0x00
constexpr int INIT_U4 = 2621440 / 16;       // 163840 uint4 stores
constexpr int INIT_FF_U4 = 1572864 / 16;    // first 98304 are 0xFF

__device__ inline u16 f2h(float f) {  // f32 -> f16 RNE (hardware cvt)
  _Float16 h = (_Float16)f;
  return __builtin_bit_cast(u16, h);
}

// ---------------- Kernel 0: workspace init (replaces 2 hipMemsetAsync)
__global__ __launch_bounds__(256) void init_kernel(uint4* __restrict__ ws4) {
  const int i = blockIdx.x * 256 + threadIdx.x;  // grid 640 * 256 = 163840
  const unsigned v = (i < INIT_FF_U4) ? 0xFFFFFFFFu : 0u;
  ws4[i] = make_uint4(v, v, v, v);
}

// ---------------- Kernel A: per-column sum / sumsq of f32 input.
// f64 regs; deterministic int fixed-point atomics into 64 shadow arrays.
__global__ __launch_bounds__(256, 4) void colstats_kernel(
    const float4* __restrict__ xv,  // f32 features, 8388608 float4s
    u64* __restrict__ shad) {
  const int t = threadIdx.x;
  const int L = blockIdx.x * 256 + t;  // 1024 blocks * 256 = 262144 threads
  double s0 = 0, s1 = 0, s2 = 0, s3 = 0, q0 = 0, q1 = 0, q2 = 0, q3 = 0;
  for (int mm = 0; mm < 32; mm += 8) {
    float4 v[8];
#pragma unroll
    for (int u = 0; u < 8; u++) v[u] = xv[L + (mm + u) * 262144];
#pragma unroll
    for (int u = 0; u < 8; u++) {
      double a = (double)v[u].x, b = (double)v[u].y;
      double c = (double)v[u].z, d = (double)v[u].w;
      s0 += a; s1 += b; s2 += c; s3 += d;
      q0 += a * a; q1 += b * b; q2 += c * c; q3 += d * d;
    }
  }
  __shared__ double red[256 * 8];  // 16 KB
  red[t * 8 + 0] = s0; red[t * 8 + 1] = s1; red[t * 8 + 2] = s2; red[t * 8 + 3] = s3;
  red[t * 8 + 4] = q0; red[t * 8 + 5] = q1; red[t * 8 + 6] = q2; red[t * 8 + 7] = q3;
  __syncthreads();
  if (t < 128) {
    // threads t and t+128 own the same 4 columns (262144 % 128 == 0)
    double v[8];
#pragma unroll
    for (int u = 0; u < 8; u++) v[u] = red[t * 8 + u] + red[(t + 128) * 8 + u];
    const int c0 = 4 * t;
    u64* sh = shad + (size_t)(blockIdx.x & (NSHADOW - 1)) * 1024;
#pragma unroll
    for (int u = 0; u < 4; u++) {
      long long a = (long long)llrint(v[u] * FXSCALE);
      long long b = (long long)llrint(v[4 + u] * FXSCALE);
      atomicAdd(&sh[c0 + u], (u64)a);
      atomicAdd(&sh[512 + c0 + u], (u64)b);
    }
  }
}

// ---------------- Kernel A2: parallel shadow merge (exact int adds, any
// order). 4 blocks x 256: thread c sums shad[sh][c] over 64 shadows,
// coalesced per iteration. Replaces the single-CU latency-bound loop that
// lived inside finalize.
__global__ __launch_bounds__(256) void merge_kernel(
    const u64* __restrict__ shad, long long* __restrict__ merged) {
  const int c = blockIdx.x * 256 + threadIdx.x;  // 0..1023
  long long s = 0;
#pragma unroll 8
  for (int sh = 0; sh < NSHADOW; sh++) s += (long long)shad[sh * 1024 + c];
  merged[c] = s;
}

// ---------------- Kernel B: finalize mean/inv-sigma (f64) from merged sums
// (8 KB, L2-hot), emit Qd f64 (recheck), f16 B-fragments in MFMA lane
// order, cd, cf. Deterministic.
__global__ __launch_bounds__(512) void finalize_kernel(
    const float* __restrict__ P,  // f32 [512][32]
    const long long* __restrict__ merged,
    double* __restrict__ Qd, u16* __restrict__ qfrag,
    double* __restrict__ cd, float* __restrict__ cf) {
  __shared__ double meanArr[FEAT];
  __shared__ double invArr[FEAT];
  __shared__ double part[16][NBINS];
  const int t = threadIdx.x;  // t = feature index, 512 threads
  const long long isum = merged[t];
  const long long isumsq = merged[512 + t];
  const double Nd = (double)N;
  const double tot = 1e-4 + Nd;
  double s = (double)isum * (1.0 / FXSCALE);
  double ss = (double)isumsq * (1.0 / FXSCALE);
  double bm = s / Nd;
  double bv = (ss - s * s / Nd) / (Nd - 1.0);  // unbiased var
  double mean = bm * Nd / tot;
  double M2 = 1e-4 + bv * Nd + bm * bm * 1e-4 * Nd / tot;
  double var = M2 / tot;
  double inv = 1.0 / sqrt(var + 1e-8);
  meanArr[t] = mean;
  invArr[t] = inv;
  // scatter f16 B-fragments (MFMA B lane order) + f64 Q for recheck
  const int ch = t >> 7, ks = (t >> 5) & 3, kg = (t >> 3) & 3, jlo = t & 7;
#pragma unroll
  for (int j = 0; j < NBINS; j++) {
    double qd = (double)P[t * NBINS + j] * inv;
    Qd[t * NBINS + j] = qd;
    const int lane = (j & 15) | (kg << 4);
    const int bt = j >> 4;
    qfrag[(size_t)((((ch * 4 + ks) * 2 + bt) * 64 + lane) * 8 + jlo)] =
        f2h((float)qd);
  }
  __syncthreads();
  // c reduction: thread t handles bin j=t&31, feature block g=t>>5 (32 feats)
  {
    const int j = t & 31, g = t >> 5;
    double p = 0.0;
    for (int f = g * 32; f < g * 32 + 32; f++) {
      double qd = (double)P[f * NBINS + j] * invArr[f];
      p += meanArr[f] * qd;
    }
    part[g][j] = p;
  }
  __syncthreads();
  if (t < NBINS) {
    double c = 0.0;
    for (int g = 0; g < 16; g++) c += part[g][t];  // fixed order -> deterministic
    cd[t] = c;
    cf[t] = (float)c;
  }
}

// ---------------- Kernel C: single-term f16 MFMA projection, direct
// global->register A-fragments (no LDS, no barriers). Lane l of wave w loads
// X[rowBase+w*16+(l&15)][ch*128+ks*32+(l>>4)*8 .. +8] — 32 contiguous bytes,
// wave touches 16 rows x 128 B (full cache lines). TAU = 4e-3 (~16 sigma of
// the f16 margin error over K=512); borderline bins re-decided by the
// wave-cooperative f64 dot. Key assembly via __shfl_xor OR-reduce.
constexpr float TAU = 4e-3f;
__global__ __launch_bounds__(256) void project_kernel(
    const float* __restrict__ feat,
    const u16* __restrict__ qfrag, const float* __restrict__ cf,
    const double* __restrict__ Qd, const double* __restrict__ cd,
    u64* __restrict__ keys_tab, int* __restrict__ head,
    unsigned* __restrict__ cnt, int* __restrict__ slot, int* __restrict__ nxt) {
  const int t = threadIdx.x;
  const int lane = t & 63;
  const int w = t >> 6;  // wave id: owns rows rowBase + w*16 .. +16, all 32 bins
  const int rowBase = blockIdx.x * 64;
  const int arow = rowBase + w * 16 + (lane & 15);     // A-frag row
  const float* xbase = feat + (size_t)arow * FEAT + (lane >> 4) * 8;

  f32x4 acc0 = {0.f, 0.f, 0.f, 0.f};  // bins 0..15
  f32x4 acc1 = {0.f, 0.f, 0.f, 0.f};  // bins 16..31
  for (int ch = 0; ch < 4; ch++) {  // K chunks of 128
    // B-fragments for this chunk -> 32 VGPRs (coalesced, L2-hot)
    s16x8 B[4][2];
#pragma unroll
    for (int ks = 0; ks < 4; ks++)
#pragma unroll
      for (int bt = 0; bt < 2; bt++)
        B[ks][bt] = *(const s16x8*)&qfrag[(size_t)((((ch * 4 + ks) * 2 + bt) * 64 + lane) * 8)];
#pragma unroll
    for (int ks = 0; ks < 4; ks++) {
      float4 x0 = *(const float4*)(xbase + ch * 128 + ks * 32);
      float4 x1 = *(const float4*)(xbase + ch * 128 + ks * 32 + 4);
      f16x8 a;
      a[0] = (_Float16)x0.x; a[1] = (_Float16)x0.y;
      a[2] = (_Float16)x0.z; a[3] = (_Float16)x0.w;
      a[4] = (_Float16)x1.x; a[5] = (_Float16)x1.y;
      a[6] = (_Float16)x1.z; a[7] = (_Float16)x1.w;
      acc0 = __builtin_amdgcn_mfma_f32_16x16x32_f16(
          a, __builtin_bit_cast(f16x8, B[ks][0]), acc0, 0, 0, 0);
      acc1 = __builtin_amdgcn_mfma_f32_16x16x32_f16(
          a, __builtin_bit_cast(f16x8, B[ks][1]), acc1, 0, 0, 0);
    }
  }
  // C/D layout (verified): col(bin) = lane&15, row = (lane>>4)*4 + reg
  const int colbin = lane & 15;
  float m0[4], m1[4];
  bool b0[4], b1[4];
  const float c0v = cf[colbin], c1v = cf[16 + colbin];
#pragma unroll
  for (int rg = 0; rg < 4; rg++) {
    m0[rg] = acc0[rg] - c0v;
    m1[rg] = acc1[rg] - c1v;
    b0[rg] = m0[rg] > 0.0f;
    b1[rg] = m1[rg] > 0.0f;
  }
  // wave-cooperative f64 recheck of borderline bins (uniform control flow)
#pragma unroll
  for (int bt = 0; bt < 2; bt++)
#pragma unroll
    for (int rg = 0; rg < 4; rg++) {
      const float mv = (bt == 0) ? m0[rg] : m1[rg];
      u64 mask = __ballot(fabsf(mv) < TAU);
      while (mask) {
        const int L = (int)__builtin_ctzll(mask);
        mask &= mask - 1;
        const int jj = bt * 16 + (L & 15);
        const int row = rowBase + w * 16 + (L >> 4) * 4 + rg;
        const float* xr = feat + (size_t)row * FEAT + lane * 8;
        const double* qp = Qd + (size_t)(lane * 8) * NBINS + jj;
        double p = 0.0;
#pragma unroll
        for (int u = 0; u < 8; u++) p = fma((double)xr[u], qp[u * NBINS], p);
#pragma unroll
        for (int off = 32; off > 0; off >>= 1) p += __shfl_xor(p, off, 64);
        const bool bit = p > cd[jj];
        if (lane == L) {
          if (bt == 0) b0[rg] = bit; else b1[rg] = bit;
        }
      }
    }
  // per-row key: OR-reduce each rg's bits over the 16-lane group.
  unsigned kb0 = (b0[0] ? (1u << colbin) : 0u) | (b1[0] ? (1u << (16 + colbin)) : 0u);
  unsigned kb1 = (b0[1] ? (1u << colbin) : 0u) | (b1[1] ? (1u << (16 + colbin)) : 0u);
  unsigned kb2 = (b0[2] ? (1u << colbin) : 0u) | (b1[2] ? (1u << (16 + colbin)) : 0u);
  unsigned kb3 = (b0[3] ? (1u << colbin) : 0u) | (b1[3] ? (1u << (16 + colbin)) : 0u);
#pragma unroll
  for (int off = 1; off < 16; off <<= 1) {
    kb0 |= __shfl_xor(kb0, off, 64);
    kb1 |= __shfl_xor(kb1, off, 64);
    kb2 |= __shfl_xor(kb2, off, 64);
    kb3 |= __shfl_xor(kb3, off, 64);
  }
  // lanes with (lane&15) < 4 insert row (lane>>4)*4 + (lane&15)
  const int sub = lane & 15;
  if (sub < 4) {
    const unsigned key = sub == 0 ? kb0 : sub == 1 ? kb1 : sub == 2 ? kb2 : kb3;
    const int i = rowBase + w * 16 + (lane >> 4) * 4 + sub;
    const u64 combined = (u64)key;  // JAX int32 semantics: env<<32 vanished
    unsigned idx = (unsigned)((combined * 0x9E3779B97F4A7C15ull) >> 47) & TABMASK;
    for (;;) {
      u64 prev = atomicCAS(&keys_tab[idx], EMPTY, combined);
      if (prev == EMPTY || prev == combined) break;
      idx = (idx + 1) & TABMASK;
    }
    slot[i] = (int)idx;
    atomicAdd(&cnt[idx], 1u);
    nxt[i] = atomicExch(&head[idx], i);
  }
}

// ---------------- Kernel D: occurrence rank -> reward (order-independent)
__global__ __launch_bounds__(256) void count_kernel(
    const int* __restrict__ slot, const int* __restrict__ nxt,
    const int* __restrict__ head, const unsigned* __restrict__ cnt,
    float* __restrict__ out) {
  const int i = blockIdx.x * 256 + threadIdx.x;
  const int sl = slot[i];
  const unsigned c = cnt[sl];
  float r = 1.0f;
  if (c > 1u) {
    int j = head[sl];
    int occ = 1;
    while (j >= 0) {
      occ += (j < i) ? 1 : 0;
      j = nxt[j];
    }
    r = 1.0f / sqrtf((float)occ);
  }
  out[i] = r;
}

extern "C" void kernel_launch(void* const* d_in, const int* in_sizes, int n_in,
                              void* d_out, int out_size, void* d_ws, size_t ws_size,
                              hipStream_t stream) {
  const float4* xv = (const float4*)d_in[0];  // features f32 [64*1024][512]
  const float* feat = (const float*)d_in[0];
  const float* proj = (const float*)d_in[1];  // random_projection f32 [512][32]
  float* out = (float*)d_out;                 // [65536] f32
  char* ws = (char*)d_ws;

  u64* keys_tab = (u64*)(ws + OFF_KEYS);
  int* head = (int*)(ws + OFF_HEAD);
  unsigned* cnt = (unsigned*)(ws + OFF_CNT);
  u64* shad = (u64*)(ws + OFF_SHAD);
  double* Qd = (double*)(ws + OFF_QD);
  double* cd = (double*)(ws + OFF_CD);
  float* cf = (float*)(ws + OFF_CF);
  int* slot = (int*)(ws + OFF_SLOT);
  int* nxt = (int*)(ws + OFF_NEXT);
  u16* qfrag = (u16*)(ws + OFF_QFRAG);
  long long* merged = (long long*)(ws + OFF_MERGE);

  init_kernel<<<INIT_U4 / 256, 256, 0, stream>>>((uint4*)ws);
  colstats_kernel<<<1024, 256, 0, stream>>>(xv, shad);
  merge_kernel<<<4, 256, 0, stream>>>(shad, merged);
  finalize_kernel<<<1, 512, 0, stream>>>(proj, merged, Qd, qfrag, cd, cf);
  project_kernel<<<N / 64, 256, 0, stream>>>(feat, qfrag, cf, Qd, cd,
                                             keys_tab, head, cnt, slot, nxt);
  count_kernel<<<N / 256, 256, 0, stream>>>(slot, nxt, head, cnt, out);
}

// Round 8
// 253.384 us; speedup vs baseline: 1.0733x; 1.0502x over previous
//
#include <hip/hip_runtime.h>

using u16 = unsigned short;
using u64 = unsigned long long;
typedef short s16x8 __attribute__((ext_vector_type(8)));
typedef _Float16 f16x8 __attribute__((ext_vector_type(8)));
typedef float f32x4 __attribute__((ext_vector_type(4)));

// Problem constants (fixed by reference)
constexpr int BATCH = 64, SEQ = 1024, FEAT = 512, NBINS = 32;
constexpr int N = BATCH * SEQ;              // 65536 samples
constexpr int TAB = 131072;                 // hash table slots (2N), pow2
constexpr unsigned TABMASK = TAB - 1;
constexpr u64 EMPTY = ~0ull;                // combined <= 2^32-1, safe sentinel
constexpr double FXSCALE = 67108864.0;      // 2^26 fixed-point for stats
constexpr int NBLK_A = 512;                 // colstats grid (512 x 512 thr)

// NOTE: JAX reference under default config runs int64 as int32;
// left_shift(env, 32) on int32 is 0 in XLA -> combined id is the 32-bit key
// ONLY (env dropped). Verified across rounds: absmax 0.0.
// NOTE (R3): NO __threadfence() in wide kernels (8-XCD L2 flush, +235 us).
// NOTE (R6): project ~L3 floor since R1; single-CU latency tails dominate.
// NOTE (R8): colstats made atomic-free (block-private partials + 2-level
// merge); init fused into colstats (disjoint addresses, boundary ordering).

// Workspace layout (bytes)
constexpr size_t OFF_KEYS = 0;              // u64[TAB]        1048576 (init FF)
constexpr size_t OFF_HEAD = 1048576;        // i32[TAB]        524288  (init FF)
constexpr size_t OFF_CNT = 1572864;         // u32[TAB]        524288  (init 00)
constexpr size_t OFF_MERGE = 2097152;       // u64[1024]       8192    (init 00)
constexpr size_t OFF_PART = 2105344;        // i64[512][1024]  4194304 (no init)
constexpr size_t OFF_QD = 6299648;          // f64[16384]      131072
constexpr size_t OFF_CD = 6430720;          // f64[32]         256
constexpr size_t OFF_CF = 6430976;          // f32[32]         128
constexpr size_t OFF_SLOT = 6431104;        // i32[N]          262144
constexpr size_t OFF_NEXT = 6693248;        // i32[N]          262144
constexpr size_t OFF_QFRAG = 6955392;       // u16[16384]      32768 f16 B-frags
// qfrag layout: [ch(4)][ks(4)][bt(2)][lane(64)][j(8)] f16 bits
// element = B[k][bin], k = ch*128+ks*32+(lane>>4)*8+j, bin = bt*16+(lane&15)

// init span (contiguous): [0, 1572864) = 0xFF, [1572864, 2105344) = 0x00
constexpr int INIT_FF_U4 = 1572864 / 16;    // 98304
constexpr int INIT_TOT_U4 = 2105344 / 16;   // 131584

__device__ inline u16 f2h(float f) {  // f32 -> f16 RNE (hardware cvt)
  _Float16 h = (_Float16)f;
  return __builtin_bit_cast(u16, h);
}

// ---------------- Kernel A: fused init + per-column sum/sumsq.
// 512 blocks x 512 threads. Init: thread T < 131584 writes one uint4
// (FF for keys/head, 00 for cnt/merged) — disjoint from streaming, ordered
// for consumers by kernel boundary. Stats: f64 accum, block-level LDS
// reduce, fixed-point block partial to PRIVATE slot (plain stores, 0 atomics).
__global__ __launch_bounds__(512, 4) void colstats_kernel(
    const float4* __restrict__ xv,  // f32 features, 8388608 float4s
    uint4* __restrict__ ws4,        // workspace base for init
    long long* __restrict__ part) { // [512][1024] block partials
  const int t = threadIdx.x;
  const int L = blockIdx.x * 512 + t;  // 0..262143
  // fused workspace init
  if (L < INIT_TOT_U4) {
    const unsigned v = (L < INIT_FF_U4) ? 0xFFFFFFFFu : 0u;
    ws4[L] = make_uint4(v, v, v, v);
  }
  double s0 = 0, s1 = 0, s2 = 0, s3 = 0, q0 = 0, q1 = 0, q2 = 0, q3 = 0;
  for (int mm = 0; mm < 32; mm += 8) {
    float4 v[8];
#pragma unroll
    for (int u = 0; u < 8; u++) v[u] = xv[L + (mm + u) * 262144];
#pragma unroll
    for (int u = 0; u < 8; u++) {
      double a = (double)v[u].x, b = (double)v[u].y;
      double c = (double)v[u].z, d = (double)v[u].w;
      s0 += a; s1 += b; s2 += c; s3 += d;
      q0 += a * a; q1 += b * b; q2 += c * c; q3 += d * d;
    }
  }
  __shared__ double red[512 * 8];  // 32 KB
  red[t * 8 + 0] = s0; red[t * 8 + 1] = s1; red[t * 8 + 2] = s2; red[t * 8 + 3] = s3;
  red[t * 8 + 4] = q0; red[t * 8 + 5] = q1; red[t * 8 + 6] = q2; red[t * 8 + 7] = q3;
  __syncthreads();
  if (t < 128) {
    // threads t, t+128, t+256, t+384 own the same 4 columns (262144%128==0)
    double v[8];
#pragma unroll
    for (int u = 0; u < 8; u++)
      v[u] = ((red[t * 8 + u] + red[(t + 128) * 8 + u]) +
              red[(t + 256) * 8 + u]) + red[(t + 384) * 8 + u];  // fixed order
    const int c0 = 4 * t;
    long long* pp = part + (size_t)blockIdx.x * 1024;
#pragma unroll
    for (int u = 0; u < 4; u++) {
      pp[c0 + u] = (long long)llrint(v[u] * FXSCALE);
      pp[512 + c0 + u] = (long long)llrint(v[4 + u] * FXSCALE);
    }
  }
}

// ---------------- Kernel A2: two-level merge of block partials.
// 64 blocks x 256 = 16384 threads = 16 groups x 1024 columns; each thread
// sums 32 partials (coalesced per b-iteration) then one atomicAdd into
// merged[c] (16K atomics total; exact int adds, order-free).
__global__ __launch_bounds__(256) void merge_kernel(
    const long long* __restrict__ part, u64* __restrict__ merged) {
  const int T = blockIdx.x * 256 + threadIdx.x;  // 0..16383
  const int c = T & 1023, g = T >> 10;           // column, group
  long long s = 0;
#pragma unroll 8
  for (int b = g * 32; b < g * 32 + 32; b++) s += part[(size_t)b * 1024 + c];
  atomicAdd(&merged[c], (u64)s);
}

// ---------------- Kernel B: finalize mean/inv-sigma (f64) from merged sums
// (8 KB, L2-hot), emit Qd f64 (recheck), f16 B-fragments in MFMA lane
// order, cd, cf. Deterministic.
__global__ __launch_bounds__(512) void finalize_kernel(
    const float* __restrict__ P,  // f32 [512][32]
    const u64* __restrict__ merged,
    double* __restrict__ Qd, u16* __restrict__ qfrag,
    double* __restrict__ cd, float* __restrict__ cf) {
  __shared__ double meanArr[FEAT];
  __shared__ double invArr[FEAT];
  __shared__ double part[16][NBINS];
  const int t = threadIdx.x;  // t = feature index, 512 threads
  const long long isum = (long long)merged[t];
  const long long isumsq = (long long)merged[512 + t];
  const double Nd = (double)N;
  const double tot = 1e-4 + Nd;
  double s = (double)isum * (1.0 / FXSCALE);
  double ss = (double)isumsq * (1.0 / FXSCALE);
  double bm = s / Nd;
  double bv = (ss - s * s / Nd) / (Nd - 1.0);  // unbiased var
  double mean = bm * Nd / tot;
  double M2 = 1e-4 + bv * Nd + bm * bm * 1e-4 * Nd / tot;
  double var = M2 / tot;
  double inv = 1.0 / sqrt(var + 1e-8);
  meanArr[t] = mean;
  invArr[t] = inv;
  // scatter f16 B-fragments (MFMA B lane order) + f64 Q for recheck
  const int ch = t >> 7, ks = (t >> 5) & 3, kg = (t >> 3) & 3, jlo = t & 7;
#pragma unroll
  for (int j = 0; j < NBINS; j++) {
    double qd = (double)P[t * NBINS + j] * inv;
    Qd[t * NBINS + j] = qd;
    const int lane = (j & 15) | (kg << 4);
    const int bt = j >> 4;
    qfrag[(size_t)((((ch * 4 + ks) * 2 + bt) * 64 + lane) * 8 + jlo)] =
        f2h((float)qd);
  }
  __syncthreads();
  // c reduction: thread t handles bin j=t&31, feature block g=t>>5 (32 feats)
  {
    const int j = t & 31, g = t >> 5;
    double p = 0.0;
    for (int f = g * 32; f < g * 32 + 32; f++) {
      double qd = (double)P[f * NBINS + j] * invArr[f];
      p += meanArr[f] * qd;
    }
    part[g][j] = p;
  }
  __syncthreads();
  if (t < NBINS) {
    double c = 0.0;
    for (int g = 0; g < 16; g++) c += part[g][t];  // fixed order -> deterministic
    cd[t] = c;
    cf[t] = (float)c;
  }
}

// ---------------- Kernel C: single-term f16 MFMA projection, direct
// global->register A-fragments (no LDS, no barriers). TAU = 4e-3 (~16 sigma
// of the f16 margin error over K=512); borderline bins re-decided by the
// wave-cooperative f64 dot. Key assembly via __shfl_xor OR-reduce.
constexpr float TAU = 4e-3f;
__global__ __launch_bounds__(256) void project_kernel(
    const float* __restrict__ feat,
    const u16* __restrict__ qfrag, const float* __restrict__ cf,
    const double* __restrict__ Qd, const double* __restrict__ cd,
    u64* __restrict__ keys_tab, int* __restrict__ head,
    unsigned* __restrict__ cnt, int* __restrict__ slot, int* __restrict__ nxt) {
  const int t = threadIdx.x;
  const int lane = t & 63;
  const int w = t >> 6;  // wave id: owns rows rowBase + w*16 .. +16, all 32 bins
  const int rowBase = blockIdx.x * 64;
  const int arow = rowBase + w * 16 + (lane & 15);     // A-frag row
  const float* xbase = feat + (size_t)arow * FEAT + (lane >> 4) * 8;

  f32x4 acc0 = {0.f, 0.f, 0.f, 0.f};  // bins 0..15
  f32x4 acc1 = {0.f, 0.f, 0.f, 0.f};  // bins 16..31
  for (int ch = 0; ch < 4; ch++) {  // K chunks of 128
    // B-fragments for this chunk -> 32 VGPRs (coalesced, L2-hot)
    s16x8 B[4][2];
#pragma unroll
    for (int ks = 0; ks < 4; ks++)
#pragma unroll
      for (int bt = 0; bt < 2; bt++)
        B[ks][bt] = *(const s16x8*)&qfrag[(size_t)((((ch * 4 + ks) * 2 + bt) * 64 + lane) * 8)];
#pragma unroll
    for (int ks = 0; ks < 4; ks++) {
      float4 x0 = *(const float4*)(xbase + ch * 128 + ks * 32);
      float4 x1 = *(const float4*)(xbase + ch * 128 + ks * 32 + 4);
      f16x8 a;
      a[0] = (_Float16)x0.x; a[1] = (_Float16)x0.y;
      a[2] = (_Float16)x0.z; a[3] = (_Float16)x0.w;
      a[4] = (_Float16)x1.x; a[5] = (_Float16)x1.y;
      a[6] = (_Float16)x1.z; a[7] = (_Float16)x1.w;
      acc0 = __builtin_amdgcn_mfma_f32_16x16x32_f16(
          a, __builtin_bit_cast(f16x8, B[ks][0]), acc0, 0, 0, 0);
      acc1 = __builtin_amdgcn_mfma_f32_16x16x32_f16(
          a, __builtin_bit_cast(f16x8, B[ks][1]), acc1, 0, 0, 0);
    }
  }
  // C/D layout (verified): col(bin) = lane&15, row = (lane>>4)*4 + reg
  const int colbin = lane & 15;
  float m0[4], m1[4];
  bool b0[4], b1[4];
  const float c0v = cf[colbin], c1v = cf[16 + colbin];
#pragma unroll
  for (int rg = 0; rg < 4; rg++) {
    m0[rg] = acc0[rg] - c0v;
    m1[rg] = acc1[rg] - c1v;
    b0[rg] = m0[rg] > 0.0f;
    b1[rg] = m1[rg] > 0.0f;
  }
  // wave-cooperative f64 recheck of borderline bins (uniform control flow)
#pragma unroll
  for (int bt = 0; bt < 2; bt++)
#pragma unroll
    for (int rg = 0; rg < 4; rg++) {
      const float mv = (bt == 0) ? m0[rg] : m1[rg];
      u64 mask = __ballot(fabsf(mv) < TAU);
      while (mask) {
        const int L = (int)__builtin_ctzll(mask);
        mask &= mask - 1;
        const int jj = bt * 16 + (L & 15);
        const int row = rowBase + w * 16 + (L >> 4) * 4 + rg;
        const float* xr = feat + (size_t)row * FEAT + lane * 8;
        const double* qp = Qd + (size_t)(lane * 8) * NBINS + jj;
        double p = 0.0;
#pragma unroll
        for (int u = 0; u < 8; u++) p = fma((double)xr[u], qp[u * NBINS], p);
#pragma unroll
        for (int off = 32; off > 0; off >>= 1) p += __shfl_xor(p, off, 64);
        const bool bit = p > cd[jj];
        if (lane == L) {
          if (bt == 0) b0[rg] = bit; else b1[rg] = bit;
        }
      }
    }
  // per-row key: OR-reduce each rg's bits over the 16-lane group.
  unsigned kb0 = (b0[0] ? (1u << colbin) : 0u) | (b1[0] ? (1u << (16 + colbin)) : 0u);
  unsigned kb1 = (b0[1] ? (1u << colbin) : 0u) | (b1[1] ? (1u << (16 + colbin)) : 0u);
  unsigned kb2 = (b0[2] ? (1u << colbin) : 0u) | (b1[2] ? (1u << (16 + colbin)) : 0u);
  unsigned kb3 = (b0[3] ? (1u << colbin) : 0u) | (b1[3] ? (1u << (16 + colbin)) : 0u);
#pragma unroll
  for (int off = 1; off < 16; off <<= 1) {
    kb0 |= __shfl_xor(kb0, off, 64);
    kb1 |= __shfl_xor(kb1, off, 64);
    kb2 |= __shfl_xor(kb2, off, 64);
    kb3 |= __shfl_xor(kb3, off, 64);
  }
  // lanes with (lane&15) < 4 insert row (lane>>4)*4 + (lane&15)
  const int sub = lane & 15;
  if (sub < 4) {
    const unsigned key = sub == 0 ? kb0 : sub == 1 ? kb1 : sub == 2 ? kb2 : kb3;
    const int i = rowBase + w * 16 + (lane >> 4) * 4 + sub;
    const u64 combined = (u64)key;  // JAX int32 semantics: env<<32 vanished
    unsigned idx = (unsigned)((combined * 0x9E3779B97F4A7C15ull) >> 47) & TABMASK;
    for (;;) {
      u64 prev = atomicCAS(&keys_tab[idx], EMPTY, combined);
      if (prev == EMPTY || prev == combined) break;
      idx = (idx + 1) & TABMASK;
    }
    slot[i] = (int)idx;
    atomicAdd(&cnt[idx], 1u);
    nxt[i] = atomicExch(&head[idx], i);
  }
}

// ---------------- Kernel D: occurrence rank -> reward (order-independent)
__global__ __launch_bounds__(256) void count_kernel(
    const int* __restrict__ slot, const int* __restrict__ nxt,
    const int* __restrict__ head, const unsigned* __restrict__ cnt,
    float* __restrict__ out) {
  const int i = blockIdx.x * 256 + threadIdx.x;
  const int sl = slot[i];
  const unsigned c = cnt[sl];
  float r = 1.0f;
  if (c > 1u) {
    int j = head[sl];
    int occ = 1;
    while (j >= 0) {
      occ += (j < i) ? 1 : 0;
      j = nxt[j];
    }
    r = 1.0f / sqrtf((float)occ);
  }
  out[i] = r;
}

extern "C" void kernel_launch(void* const* d_in, const int* in_sizes, int n_in,
                              void* d_out, int out_size, void* d_ws, size_t ws_size,
                              hipStream_t stream) {
  const float4* xv = (const float4*)d_in[0];  // features f32 [64*1024][512]
  const float* feat = (const float*)d_in[0];
  const float* proj = (const float*)d_in[1];  // random_projection f32 [512][32]
  float* out = (float*)d_out;                 // [65536] f32
  char* ws = (char*)d_ws;

  u64* keys_tab = (u64*)(ws + OFF_KEYS);
  int* head = (int*)(ws + OFF_HEAD);
  unsigned* cnt = (unsigned*)(ws + OFF_CNT);
  u64* merged = (u64*)(ws + OFF_MERGE);
  long long* part = (long long*)(ws + OFF_PART);
  double* Qd = (double*)(ws + OFF_QD);
  double* cd = (double*)(ws + OFF_CD);
  float* cf = (float*)(ws + OFF_CF);
  int* slot = (int*)(ws + OFF_SLOT);
  int* nxt = (int*)(ws + OFF_NEXT);
  u16* qfrag = (u16*)(ws + OFF_QFRAG);

  colstats_kernel<<<NBLK_A, 512, 0, stream>>>(xv, (uint4*)ws, part);
  merge_kernel<<<64, 256, 0, stream>>>(part, merged);
  finalize_kernel<<<1, 512, 0, stream>>>(proj, merged, Qd, qfrag, cd, cf);
  project_kernel<<<N / 64, 256, 0, stream>>>(feat, qfrag, cf, Qd, cd,
                                             keys_tab, head, cnt, slot, nxt);
  count_kernel<<<N / 256, 256, 0, stream>>>(slot, nxt, head, cnt, out);
}

// Round 9
// 250.448 us; speedup vs baseline: 1.0859x; 1.0117x over previous
//
#include <hip/hip_runtime.h>

using u16 = unsigned short;
using u64 = unsigned long long;
typedef short s16x8 __attribute__((ext_vector_type(8)));
typedef _Float16 f16x8 __attribute__((ext_vector_type(8)));
typedef float f32x4 __attribute__((ext_vector_type(4)));

// Problem constants (fixed by reference)
constexpr int BATCH = 64, SEQ = 1024, FEAT = 512, NBINS = 32;
constexpr int N = BATCH * SEQ;              // 65536 samples
constexpr int TAB = 131072;                 // hash table slots (2N), pow2
constexpr unsigned TABMASK = TAB - 1;
constexpr u64 EMPTY = ~0ull;                // combined <= 2^32-1, safe sentinel
constexpr double FXSCALE = 67108864.0;      // 2^26 fixed-point for stats
constexpr int NBLK_A = 256;                 // colstats grid (256 x 512 thr)

// NOTE: JAX reference under default config runs int64 as int32;
// left_shift(env, 32) on int32 is 0 in XLA -> combined id is the 32-bit key
// ONLY (env dropped). Verified across rounds: absmax 0.0.
// NOTE (R3): NO __threadfence() in wide kernels (8-XCD L2 flush, +235 us).
// NOTE (R6): project ~L3 floor since R1; single-CU latency tails dominate.
// NOTE (R9): partials 4->2 MB (256 colstats blocks), merge 32 blocks,
// finalize widened to 1024 threads. If null -> structural floor reached.

// Workspace layout (bytes)
constexpr size_t OFF_KEYS = 0;              // u64[TAB]        1048576 (init FF)
constexpr size_t OFF_HEAD = 1048576;        // i32[TAB]        524288  (init FF)
constexpr size_t OFF_CNT = 1572864;         // u32[TAB]        524288  (init 00)
constexpr size_t OFF_MERGE = 2097152;       // u64[1024]       8192    (init 00)
constexpr size_t OFF_PART = 2105344;        // i64[256][1024]  2097152 (no init)
constexpr size_t OFF_QD = 4202496;          // f64[16384]      131072
constexpr size_t OFF_CD = 4333568;          // f64[32]         256
constexpr size_t OFF_CF = 4333824;          // f32[32]         128
constexpr size_t OFF_SLOT = 4333952;        // i32[N]          262144
constexpr size_t OFF_NEXT = 4596096;        // i32[N]          262144
constexpr size_t OFF_QFRAG = 4858240;       // u16[16384]      32768 f16 B-frags
// qfrag layout: [ch(4)][ks(4)][bt(2)][lane(64)][j(8)] f16 bits
// element = B[k][bin], k = ch*128+ks*32+(lane>>4)*8+j, bin = bt*16+(lane&15)

// init span (contiguous): [0, 1572864) = 0xFF, [1572864, 2105344) = 0x00
constexpr int INIT_FF_U4 = 1572864 / 16;    // 98304
constexpr int INIT_TOT_U4 = 2105344 / 16;   // 131584

__device__ inline u16 f2h(float f) {  // f32 -> f16 RNE (hardware cvt)
  _Float16 h = (_Float16)f;
  return __builtin_bit_cast(u16, h);
}

// ---------------- Kernel A: fused init + per-column sum/sumsq.
// 256 blocks x 512 threads, grid-stride x2 vs R8 (same HBM traffic, half
// the partial volume). Init fused (disjoint addresses, boundary ordering).
// f64 accum, block LDS reduce, fixed-point partial to PRIVATE slot (0 atomics).
__global__ __launch_bounds__(512, 4) void colstats_kernel(
    const float4* __restrict__ xv,  // f32 features, 8388608 float4s
    uint4* __restrict__ ws4,        // workspace base for init
    long long* __restrict__ part) { // [256][1024] block partials
  const int t = threadIdx.x;
  const int L = blockIdx.x * 512 + t;  // 0..131071
  // fused workspace init (131584 uint4 total; thread L covers L and maybe
  // L + 131072)
  {
    const unsigned v = (L < INIT_FF_U4) ? 0xFFFFFFFFu : 0u;
    ws4[L] = make_uint4(v, v, v, v);
    if (L < INIT_TOT_U4 - 131072) ws4[L + 131072] = make_uint4(0u, 0u, 0u, 0u);
  }
  double s0 = 0, s1 = 0, s2 = 0, s3 = 0, q0 = 0, q1 = 0, q2 = 0, q3 = 0;
  for (int mm = 0; mm < 64; mm += 8) {
    float4 v[8];
#pragma unroll
    for (int u = 0; u < 8; u++) v[u] = xv[L + (mm + u) * 131072];
#pragma unroll
    for (int u = 0; u < 8; u++) {
      double a = (double)v[u].x, b = (double)v[u].y;
      double c = (double)v[u].z, d = (double)v[u].w;
      s0 += a; s1 += b; s2 += c; s3 += d;
      q0 += a * a; q1 += b * b; q2 += c * c; q3 += d * d;
    }
  }
  __shared__ double red[512 * 8];  // 32 KB
  red[t * 8 + 0] = s0; red[t * 8 + 1] = s1; red[t * 8 + 2] = s2; red[t * 8 + 3] = s3;
  red[t * 8 + 4] = q0; red[t * 8 + 5] = q1; red[t * 8 + 6] = q2; red[t * 8 + 7] = q3;
  __syncthreads();
  if (t < 128) {
    // threads t, t+128, t+256, t+384 own the same 4 columns (131072%128==0)
    double v[8];
#pragma unroll
    for (int u = 0; u < 8; u++)
      v[u] = ((red[t * 8 + u] + red[(t + 128) * 8 + u]) +
              red[(t + 256) * 8 + u]) + red[(t + 384) * 8 + u];  // fixed order
    const int c0 = 4 * t;
    long long* pp = part + (size_t)blockIdx.x * 1024;
#pragma unroll
    for (int u = 0; u < 4; u++) {
      pp[c0 + u] = (long long)llrint(v[u] * FXSCALE);
      pp[512 + c0 + u] = (long long)llrint(v[4 + u] * FXSCALE);
    }
  }
}

// ---------------- Kernel A2: two-level merge of block partials.
// 32 blocks x 256 = 8192 threads = 8 groups x 1024 columns; each thread
// sums 32 partials (coalesced) then one atomicAdd into merged[c]
// (8K atomics; exact int adds, order-free).
__global__ __launch_bounds__(256) void merge_kernel(
    const long long* __restrict__ part, u64* __restrict__ merged) {
  const int T = blockIdx.x * 256 + threadIdx.x;  // 0..8191
  const int c = T & 1023, g = T >> 10;           // column, group (0..7)
  long long s = 0;
#pragma unroll 8
  for (int b = g * 32; b < g * 32 + 32; b++) s += part[(size_t)b * 1024 + c];
  atomicAdd(&merged[c], (u64)s);
}

// ---------------- Kernel B: finalize mean/inv-sigma (f64) from merged sums,
// emit Qd f64 (recheck), f16 B-fragments in MFMA lane order, cd, cf.
// 1024 threads: stats per-feature on t<512; scatter + c-reduction use all.
__global__ __launch_bounds__(1024) void finalize_kernel(
    const float* __restrict__ P,  // f32 [512][32]
    const u64* __restrict__ merged,
    double* __restrict__ Qd, u16* __restrict__ qfrag,
    double* __restrict__ cd, float* __restrict__ cf) {
  __shared__ double meanArr[FEAT];
  __shared__ double invArr[FEAT];
  __shared__ double part[32][NBINS];
  const int t = threadIdx.x;
  if (t < FEAT) {
    const long long isum = (long long)merged[t];
    const long long isumsq = (long long)merged[512 + t];
    const double Nd = (double)N;
    const double tot = 1e-4 + Nd;
    double s = (double)isum * (1.0 / FXSCALE);
    double ss = (double)isumsq * (1.0 / FXSCALE);
    double bm = s / Nd;
    double bv = (ss - s * s / Nd) / (Nd - 1.0);  // unbiased var
    double mean = bm * Nd / tot;
    double M2 = 1e-4 + bv * Nd + bm * bm * 1e-4 * Nd / tot;
    double var = M2 / tot;
    double inv = 1.0 / sqrt(var + 1e-8);
    meanArr[t] = mean;
    invArr[t] = inv;
  }
  __syncthreads();
  // scatter f16 B-fragments + f64 Q: 1024 threads, each 16 bins of feature f
  {
    const int f = t & 511, jh = t >> 9;  // jh in {0,1}
    const double inv = invArr[f];
    const int ch = f >> 7, ks = (f >> 5) & 3, kg = (f >> 3) & 3, jlo = f & 7;
#pragma unroll
    for (int jj = 0; jj < 16; jj++) {
      const int j = jh * 16 + jj;
      double qd = (double)P[f * NBINS + j] * inv;
      Qd[f * NBINS + j] = qd;
      const int lane = (j & 15) | (kg << 4);
      const int bt = j >> 4;
      qfrag[(size_t)((((ch * 4 + ks) * 2 + bt) * 64 + lane) * 8 + jlo)] =
          f2h((float)qd);
    }
  }
  __syncthreads();
  // c reduction: thread t handles bin j=t&31, feature block g=t>>5 (16 feats)
  {
    const int j = t & 31, g = t >> 5;
    double p = 0.0;
    for (int f = g * 16; f < g * 16 + 16; f++) {
      double qd = (double)P[f * NBINS + j] * invArr[f];
      p += meanArr[f] * qd;
    }
    part[g][j] = p;
  }
  __syncthreads();
  if (t < NBINS) {
    double c = 0.0;
    for (int g = 0; g < 32; g++) c += part[g][t];  // fixed order -> deterministic
    cd[t] = c;
    cf[t] = (float)c;
  }
}

// ---------------- Kernel C: single-term f16 MFMA projection, direct
// global->register A-fragments (no LDS, no barriers). TAU = 4e-3 (~16 sigma
// of the f16 margin error over K=512); borderline bins re-decided by the
// wave-cooperative f64 dot. Key assembly via __shfl_xor OR-reduce.
constexpr float TAU = 4e-3f;
__global__ __launch_bounds__(256) void project_kernel(
    const float* __restrict__ feat,
    const u16* __restrict__ qfrag, const float* __restrict__ cf,
    const double* __restrict__ Qd, const double* __restrict__ cd,
    u64* __restrict__ keys_tab, int* __restrict__ head,
    unsigned* __restrict__ cnt, int* __restrict__ slot, int* __restrict__ nxt) {
  const int t = threadIdx.x;
  const int lane = t & 63;
  const int w = t >> 6;  // wave id: owns rows rowBase + w*16 .. +16, all 32 bins
  const int rowBase = blockIdx.x * 64;
  const int arow = rowBase + w * 16 + (lane & 15);     // A-frag row
  const float* xbase = feat + (size_t)arow * FEAT + (lane >> 4) * 8;

  f32x4 acc0 = {0.f, 0.f, 0.f, 0.f};  // bins 0..15
  f32x4 acc1 = {0.f, 0.f, 0.f, 0.f};  // bins 16..31
  for (int ch = 0; ch < 4; ch++) {  // K chunks of 128
    // B-fragments for this chunk -> 32 VGPRs (coalesced, L2-hot)
    s16x8 B[4][2];
#pragma unroll
    for (int ks = 0; ks < 4; ks++)
#pragma unroll
      for (int bt = 0; bt < 2; bt++)
        B[ks][bt] = *(const s16x8*)&qfrag[(size_t)((((ch * 4 + ks) * 2 + bt) * 64 + lane) * 8)];
#pragma unroll
    for (int ks = 0; ks < 4; ks++) {
      float4 x0 = *(const float4*)(xbase + ch * 128 + ks * 32);
      float4 x1 = *(const float4*)(xbase + ch * 128 + ks * 32 + 4);
      f16x8 a;
      a[0] = (_Float16)x0.x; a[1] = (_Float16)x0.y;
      a[2] = (_Float16)x0.z; a[3] = (_Float16)x0.w;
      a[4] = (_Float16)x1.x; a[5] = (_Float16)x1.y;
      a[6] = (_Float16)x1.z; a[7] = (_Float16)x1.w;
      acc0 = __builtin_amdgcn_mfma_f32_16x16x32_f16(
          a, __builtin_bit_cast(f16x8, B[ks][0]), acc0, 0, 0, 0);
      acc1 = __builtin_amdgcn_mfma_f32_16x16x32_f16(
          a, __builtin_bit_cast(f16x8, B[ks][1]), acc1, 0, 0, 0);
    }
  }
  // C/D layout (verified): col(bin) = lane&15, row = (lane>>4)*4 + reg
  const int colbin = lane & 15;
  float m0[4], m1[4];
  bool b0[4], b1[4];
  const float c0v = cf[colbin], c1v = cf[16 + colbin];
#pragma unroll
  for (int rg = 0; rg < 4; rg++) {
    m0[rg] = acc0[rg] - c0v;
    m1[rg] = acc1[rg] - c1v;
    b0[rg] = m0[rg] > 0.0f;
    b1[rg] = m1[rg] > 0.0f;
  }
  // wave-cooperative f64 recheck of borderline bins (uniform control flow)
#pragma unroll
  for (int bt = 0; bt < 2; bt++)
#pragma unroll
    for (int rg = 0; rg < 4; rg++) {
      const float mv = (bt == 0) ? m0[rg] : m1[rg];
      u64 mask = __ballot(fabsf(mv) < TAU);
      while (mask) {
        const int L = (int)__builtin_ctzll(mask);
        mask &= mask - 1;
        const int jj = bt * 16 + (L & 15);
        const int row = rowBase + w * 16 + (L >> 4) * 4 + rg;
        const float* xr = feat + (size_t)row * FEAT + lane * 8;
        const double* qp = Qd + (size_t)(lane * 8) * NBINS + jj;
        double p = 0.0;
#pragma unroll
        for (int u = 0; u < 8; u++) p = fma((double)xr[u], qp[u * NBINS], p);
#pragma unroll
        for (int off = 32; off > 0; off >>= 1) p += __shfl_xor(p, off, 64);
        const bool bit = p > cd[jj];
        if (lane == L) {
          if (bt == 0) b0[rg] = bit; else b1[rg] = bit;
        }
      }
    }
  // per-row key: OR-reduce each rg's bits over the 16-lane group.
  unsigned kb0 = (b0[0] ? (1u << colbin) : 0u) | (b1[0] ? (1u << (16 + colbin)) : 0u);
  unsigned kb1 = (b0[1] ? (1u << colbin) : 0u) | (b1[1] ? (1u << (16 + colbin)) : 0u);
  unsigned kb2 = (b0[2] ? (1u << colbin) : 0u) | (b1[2] ? (1u << (16 + colbin)) : 0u);
  unsigned kb3 = (b0[3] ? (1u << colbin) : 0u) | (b1[3] ? (1u << (16 + colbin)) : 0u);
#pragma unroll
  for (int off = 1; off < 16; off <<= 1) {
    kb0 |= __shfl_xor(kb0, off, 64);
    kb1 |= __shfl_xor(kb1, off, 64);
    kb2 |= __shfl_xor(kb2, off, 64);
    kb3 |= __shfl_xor(kb3, off, 64);
  }
  // lanes with (lane&15) < 4 insert row (lane>>4)*4 + (lane&15)
  const int sub = lane & 15;
  if (sub < 4) {
    const unsigned key = sub == 0 ? kb0 : sub == 1 ? kb1 : sub == 2 ? kb2 : kb3;
    const int i = rowBase + w * 16 + (lane >> 4) * 4 + sub;
    const u64 combined = (u64)key;  // JAX int32 semantics: env<<32 vanished
    unsigned idx = (unsigned)((combined * 0x9E3779B97F4A7C15ull) >> 47) & TABMASK;
    for (;;) {
      u64 prev = atomicCAS(&keys_tab[idx], EMPTY, combined);
      if (prev == EMPTY || prev == combined) break;
      idx = (idx + 1) & TABMASK;
    }
    slot[i] = (int)idx;
    atomicAdd(&cnt[idx], 1u);
    nxt[i] = atomicExch(&head[idx], i);
  }
}

// ---------------- Kernel D: occurrence rank -> reward (order-independent)
__global__ __launch_bounds__(256) void count_kernel(
    const int* __restrict__ slot, const int* __restrict__ nxt,
    const int* __restrict__ head, const unsigned* __restrict__ cnt,
    float* __restrict__ out) {
  const int i = blockIdx.x * 256 + threadIdx.x;
  const int sl = slot[i];
  const unsigned c = cnt[sl];
  float r = 1.0f;
  if (c > 1u) {
    int j = head[sl];
    int occ = 1;
    while (j >= 0) {
      occ += (j < i) ? 1 : 0;
      j = nxt[j];
    }
    r = 1.0f / sqrtf((float)occ);
  }
  out[i] = r;
}

extern "C" void kernel_launch(void* const* d_in, const int* in_sizes, int n_in,
                              void* d_out, int out_size, void* d_ws, size_t ws_size,
                              hipStream_t stream) {
  const float4* xv = (const float4*)d_in[0];  // features f32 [64*1024][512]
  const float* feat = (const float*)d_in[0];
  const float* proj = (const float*)d_in[1];  // random_projection f32 [512][32]
  float* out = (float*)d_out;                 // [65536] f32
  char* ws = (char*)d_ws;

  u64* keys_tab = (u64*)(ws + OFF_KEYS);
  int* head = (int*)(ws + OFF_HEAD);
  unsigned* cnt = (unsigned*)(ws + OFF_CNT);
  u64* merged = (u64*)(ws + OFF_MERGE);
  long long* part = (long long*)(ws + OFF_PART);
  double* Qd = (double*)(ws + OFF_QD);
  double* cd = (double*)(ws + OFF_CD);
  float* cf = (float*)(ws + OFF_CF);
  int* slot = (int*)(ws + OFF_SLOT);
  int* nxt = (int*)(ws + OFF_NEXT);
  u16* qfrag = (u16*)(ws + OFF_QFRAG);

  colstats_kernel<<<NBLK_A, 512, 0, stream>>>(xv, (uint4*)ws, part);
  merge_kernel<<<32, 256, 0, stream>>>(part, merged);
  finalize_kernel<<<1, 1024, 0, stream>>>(proj, merged, Qd, qfrag, cd, cf);
  project_kernel<<<N / 64, 256, 0, stream>>>(feat, qfrag, cf, Qd, cd,
                                             keys_tab, head, cnt, slot, nxt);
  count_kernel<<<N / 256, 256, 0, stream>>>(slot, nxt, head, cnt, out);
}